// Round 2
// baseline (400.159 us; speedup 1.0000x reference)
//
#include <hip/hip_runtime.h>
#include <math.h>

#define NPV 3072
#define LDP 3073
#define EPSF 1e-8f

__device__ __forceinline__ void ins3(float v, float& a, float& b, float& c) {
    if (v > a) { c = b; b = a; a = v; }
    else if (v > b) { c = b; b = v; }
    else if (v > c) { c = v; }
}

__device__ __forceinline__ void ins4(float v, int j,
    float& a, int& ja, float& b, int& jb, float& c, int& jc, float& d, int& jd)
{
    if (v > c) {
        d = c; jd = jc;
        if (v > a)      { c = b; jc = jb; b = a; jb = ja; a = v; ja = j; }
        else if (v > b) { c = b; jc = jb; b = v; jb = j; }
        else            { c = v; jc = j; }
    } else if (v > d) { d = v; jd = j; }
}

// One block per row: top-4 (value, col) of the row. tr[i] = 3rd-largest value.
__global__ __launch_bounds__(256) void k_row_top4(const float* __restrict__ P,
        float* __restrict__ tr, float* __restrict__ cand_v, int* __restrict__ cand_j)
{
    int i = blockIdx.x, t = threadIdx.x;
    const float* row = P + (size_t)i * LDP;
    float a = -1e30f, b = -1e30f, c = -1e30f, d = -1e30f;
    int ja = -1, jb = -1, jc = -1, jd = -1;
    for (int j = t; j < NPV; j += 256) ins4(row[j], j, a, ja, b, jb, c, jc, d, jd);
    // wave reduce (64 lanes)
    for (int off = 32; off; off >>= 1) {
        float xa = __shfl_down(a, off), xb = __shfl_down(b, off);
        float xc = __shfl_down(c, off), xd = __shfl_down(d, off);
        int   ya = __shfl_down(ja, off), yb = __shfl_down(jb, off);
        int   yc = __shfl_down(jc, off), yd = __shfl_down(jd, off);
        ins4(xa, ya, a, ja, b, jb, c, jc, d, jd);
        ins4(xb, yb, a, ja, b, jb, c, jc, d, jd);
        ins4(xc, yc, a, ja, b, jb, c, jc, d, jd);
        ins4(xd, yd, a, ja, b, jb, c, jc, d, jd);
    }
    __shared__ float sv[4][4];
    __shared__ int   sj[4][4];
    int lane = t & 63, w = t >> 6;
    if (lane == 0) {
        sv[w][0] = a; sv[w][1] = b; sv[w][2] = c; sv[w][3] = d;
        sj[w][0] = ja; sj[w][1] = jb; sj[w][2] = jc; sj[w][3] = jd;
    }
    __syncthreads();
    if (t == 0) {
        for (int ww = 1; ww < 4; ++ww)
            for (int k = 0; k < 4; ++k)
                ins4(sv[ww][k], sj[ww][k], a, ja, b, jb, c, jc, d, jd);
        tr[i] = c;
        cand_v[i * 4 + 0] = a; cand_v[i * 4 + 1] = b; cand_v[i * 4 + 2] = c; cand_v[i * 4 + 3] = d;
        cand_j[i * 4 + 0] = ja; cand_j[i * 4 + 1] = jb; cand_j[i * 4 + 2] = jc; cand_j[i * 4 + 3] = jd;
    }
}

// Partial column top-3 over a row segment. grid (NPV/256, nseg).
__global__ __launch_bounds__(256) void k_col_top3_part(const float* __restrict__ P,
        float* __restrict__ part, int segrows)
{
    int j = blockIdx.x * 256 + threadIdx.x;
    int i0 = blockIdx.y * segrows;
    float a = -1e30f, b = -1e30f, c = -1e30f;
    #pragma unroll 4
    for (int i = i0; i < i0 + segrows; ++i) ins3(P[(size_t)i * LDP + j], a, b, c);
    size_t o = ((size_t)blockIdx.y * NPV + j) * 3;
    part[o] = a; part[o + 1] = b; part[o + 2] = c;
}

__global__ __launch_bounds__(256) void k_col_merge(const float* __restrict__ part,
        float* __restrict__ tc, int nseg)
{
    int j = blockIdx.x * 256 + threadIdx.x;
    float a = -1e30f, b = -1e30f, c = -1e30f;
    for (int s = 0; s < nseg; ++s) {
        size_t o = ((size_t)s * NPV + j) * 3;
        ins3(part[o], a, b, c); ins3(part[o + 1], a, b, c); ins3(part[o + 2], a, b, c);
    }
    tc[j] = c;
}

// One thread per row: filter <=4 row candidates against mask, sort by j ascending.
__global__ __launch_bounds__(256) void k_filter(const float* __restrict__ tr,
        const float* __restrict__ tc, const float* __restrict__ cand_v,
        const int* __restrict__ cand_j, int* __restrict__ rowcnt,
        int* __restrict__ rowj, float* __restrict__ roww, float* __restrict__ w1)
{
    int i = blockIdx.x * 256 + threadIdx.x;
    if (i >= NPV) return;
    float tr3 = tr[i];
    int js[4]; float vs[4]; int n = 0;
    for (int e = 0; e < 4; ++e) {
        float v = cand_v[i * 4 + e];
        int j = cand_j[i * 4 + e];
        if (v >= tr3 && v > 0.01f && v >= tc[j]) { js[n] = j; vs[n] = v; ++n; }
    }
    for (int x = 1; x < n; ++x) {
        int jx = js[x]; float vx = vs[x]; int y = x - 1;
        while (y >= 0 && js[y] > jx) { js[y + 1] = js[y]; vs[y + 1] = vs[y]; --y; }
        js[y + 1] = jx; vs[y + 1] = vx;
    }
    float s = 0.f;
    for (int x = 0; x < n; ++x) { rowj[i * 4 + x] = js[x]; roww[i * 4 + x] = vs[x]; s += vs[x]; }
    rowcnt[i] = n;
    w1[i] = s;
}

__device__ float block_reduce(float v, float* red) {
    int t = threadIdx.x;
    red[t] = v;
    __syncthreads();
    for (int s = 128; s > 0; s >>= 1) {
        if (t < s) red[t] += red[t + s];
        __syncthreads();
    }
    float r = red[0];
    __syncthreads();
    return r;
}

__device__ void mat3mul(const float* A, const float* B, float* C) {
    for (int r = 0; r < 3; ++r)
        for (int c = 0; c < 3; ++c)
            C[r * 3 + c] = A[r * 3] * B[c] + A[r * 3 + 1] * B[3 + c] + A[r * 3 + 2] * B[6 + c];
}

__device__ float det3(const float* M) {
    return M[0] * (M[4] * M[8] - M[5] * M[7])
         - M[1] * (M[3] * M[8] - M[5] * M[6])
         + M[2] * (M[3] * M[7] - M[4] * M[6]);
}

__device__ void powiter3(const float* M, float* v) {
    v[0] = v[1] = v[2] = 0.57735026918962584f;
    for (int it = 0; it < 50; ++it) {
        float y0 = M[0] * v[0] + M[1] * v[1] + M[2] * v[2];
        float y1 = M[3] * v[0] + M[4] * v[1] + M[5] * v[2];
        float y2 = M[6] * v[0] + M[7] * v[1] + M[8] * v[2];
        float n = sqrtf(y0 * y0 + y1 * y1 + y2 * y2) + EPSF;
        v[0] = y0 / n; v[1] = y1 / n; v[2] = y2 / n;
    }
}

__global__ __launch_bounds__(256) void k_final(const float* __restrict__ Kmat,
        const int* __restrict__ rowcnt, const int* __restrict__ rowj,
        const float* __restrict__ roww, const float* __restrict__ w1g,
        float* __restrict__ out)
{
    __shared__ float sW2[NPV];
    __shared__ float red[256];
    __shared__ float sKi[9];
    __shared__ float sPar[6];
    __shared__ float sMs[81];
    __shared__ float sV9[9];
    __shared__ float sMred[4 * 45];
    int t = threadIdx.x;

    if (t == 0) {
        float k00 = Kmat[0], k01 = Kmat[1], k02 = Kmat[2];
        float k10 = Kmat[3], k11 = Kmat[4], k12 = Kmat[5];
        float k20 = Kmat[6], k21 = Kmat[7], k22 = Kmat[8];
        float det = k00 * (k11 * k22 - k12 * k21) - k01 * (k10 * k22 - k12 * k20) + k02 * (k10 * k21 - k11 * k20);
        float id = 1.0f / det;
        sKi[0] = (k11 * k22 - k12 * k21) * id; sKi[1] = (k02 * k21 - k01 * k22) * id; sKi[2] = (k01 * k12 - k02 * k11) * id;
        sKi[3] = (k12 * k20 - k10 * k22) * id; sKi[4] = (k00 * k22 - k02 * k20) * id; sKi[5] = (k02 * k10 - k00 * k12) * id;
        sKi[6] = (k10 * k21 - k11 * k20) * id; sKi[7] = (k01 * k20 - k00 * k21) * id; sKi[8] = (k00 * k11 - k01 * k10) * id;
    }
    for (int j = t; j < NPV; j += 256) sW2[j] = 0.f;
    __syncthreads();

    for (int i = t; i < NPV; i += 256) {
        int n = rowcnt[i];
        for (int x = 0; x < n; ++x) atomicAdd(&sW2[rowj[i * 4 + x]], roww[i * 4 + x]);
    }
    __syncthreads();

    auto PX = [&](int i) -> float {
        float x = (float)(i & 63), y = (float)(i >> 6);
        return sKi[0] * x + sKi[1] * y + sKi[2];
    };
    auto PY = [&](int i) -> float {
        float x = (float)(i & 63), y = (float)(i >> 6);
        return sKi[3] * x + sKi[4] * y + sKi[5];
    };

    for (int set = 0; set < 2; ++set) {
        float sw = 0.f, sx = 0.f, sy = 0.f;
        for (int i = t; i < NPV; i += 256) {
            float w = set ? sW2[i] : w1g[i];
            sw += w; sx += w * PX(i); sy += w * PY(i);
        }
        sw = block_reduce(sw, red);
        sx = block_reduce(sx, red);
        sy = block_reduce(sy, red);
        float ws = sw + EPSF;
        float cx = sx / ws, cy = sy / ws;
        float smd = 0.f;
        for (int i = t; i < NPV; i += 256) {
            float w = set ? sW2[i] : w1g[i];
            float dx = PX(i) - cx, dy = PY(i) - cy;
            smd += w * (dx * dx + dy * dy);
        }
        smd = block_reduce(smd, red);
        float md = sqrtf(smd / ws + EPSF);
        float sH = 1.4142135623730951f / (md + EPSF);
        if (t == 0) { sPar[set * 3 + 0] = cx; sPar[set * 3 + 1] = cy; sPar[set * 3 + 2] = sH; }
        __syncthreads();
    }

    float c1x = sPar[0], c1y = sPar[1], s1 = sPar[2];
    float c2x = sPar[3], c2y = sPar[4], s2 = sPar[5];

    float acc[45];
    #pragma unroll
    for (int k = 0; k < 45; ++k) acc[k] = 0.f;
    for (int i = t; i < NPV; i += 256) {
        int n = rowcnt[i];
        if (n == 0) continue;
        float f1[3];
        f1[0] = (PX(i) - c1x) * s1;
        f1[1] = (PY(i) - c1y) * s1;
        f1[2] = 1.f;
        for (int e = 0; e < n; ++e) {
            int j = rowj[i * 4 + e];
            float w = roww[i * 4 + e];
            float f2[3];
            f2[0] = (PX(j) - c2x) * s2;
            f2[1] = (PY(j) - c2y) * s2;
            f2[2] = 1.f;
            float a[9];
            #pragma unroll
            for (int u = 0; u < 3; ++u)
                #pragma unroll
                for (int v = 0; v < 3; ++v) a[u * 3 + v] = f1[u] * f2[v];
            int idx = 0;
            #pragma unroll
            for (int u = 0; u < 9; ++u) {
                float wa = w * a[u];
                #pragma unroll
                for (int v = u; v < 9; ++v) { acc[idx] = fmaf(wa, a[v], acc[idx]); ++idx; }
            }
        }
    }
    int lane = t & 63, wid = t >> 6;
    #pragma unroll
    for (int k = 0; k < 45; ++k) {
        float v = acc[k];
        v += __shfl_down(v, 32);
        v += __shfl_down(v, 16);
        v += __shfl_down(v, 8);
        v += __shfl_down(v, 4);
        v += __shfl_down(v, 2);
        v += __shfl_down(v, 1);
        if (lane == 0) sMred[wid * 45 + k] = v;
    }
    __syncthreads();
    if (t == 0) {
        float M[81];
        int idx = 0;
        for (int u = 0; u < 9; ++u)
            for (int v = u; v < 9; ++v) {
                float s = sMred[idx] + sMred[45 + idx] + sMred[90 + idx] + sMred[135 + idx];
                M[u * 9 + v] = s; M[v * 9 + u] = s;
                ++idx;
            }
        float lam = 0.f;
        for (int d = 0; d < 9; ++d) lam += M[d * 9 + d];
        for (int r = 0; r < 9; ++r)
            for (int c = 0; c < 9; ++c)
                sMs[r * 9 + c] = (r == c ? lam : 0.f) - M[r * 9 + c];
    }
    __syncthreads();

    if (t < 64) {
        float mrow[9];
        #pragma unroll
        for (int c = 0; c < 9; ++c) mrow[c] = (t < 9) ? sMs[t * 9 + c] : 0.f;
        float v = (t < 9) ? (1.f / 3.f) : 0.f;
        for (int it = 0; it < 50; ++it) {
            float y = 0.f;
            #pragma unroll
            for (int c = 0; c < 9; ++c) y = fmaf(mrow[c], __shfl(v, c, 64), y);
            float q = (t < 9) ? y * y : 0.f;
            q += __shfl_xor(q, 1);
            q += __shfl_xor(q, 2);
            q += __shfl_xor(q, 4);
            q += __shfl_xor(q, 8);
            float n = sqrtf(q) + EPSF;
            v = y / n;
        }
        if (t < 9) sV9[t] = v;
    }
    __syncthreads();

    if (t == 0) {
        float Er[9];
        for (int k = 0; k < 9; ++k) Er[k] = sV9[k];
        float T1[9]  = { s1, 0.f, -s1 * c1x,   0.f, s1, -s1 * c1y,   0.f, 0.f, 1.f };
        float T2t[9] = { s2, 0.f, 0.f,   0.f, s2, 0.f,   -s2 * c2x, -s2 * c2y, 1.f };
        float M1[9], E[9];
        mat3mul(Er, T1, M1);
        mat3mul(T2t, M1, E);

        float B[9];
        for (int r = 0; r < 3; ++r)
            for (int c = 0; c < 3; ++c)
                B[r * 3 + c] = E[r] * E[c] + E[3 + r] * E[3 + c] + E[6 + r] * E[6 + c];
        float lam3 = B[0] + B[4] + B[8];
        float v1[3], v3[3], v2[3];
        powiter3(B, v1);
        float Bs[9];
        for (int k = 0; k < 9; ++k) Bs[k] = -B[k];
        Bs[0] += lam3; Bs[4] += lam3; Bs[8] += lam3;
        powiter3(Bs, v3);
        v2[0] = v3[1] * v1[2] - v3[2] * v1[1];
        v2[1] = v3[2] * v1[0] - v3[0] * v1[2];
        v2[2] = v3[0] * v1[1] - v3[1] * v1[0];
        float n2 = sqrtf(v2[0] * v2[0] + v2[1] * v2[1] + v2[2] * v2[2]) + EPSF;
        v2[0] /= n2; v2[1] /= n2; v2[2] /= n2;
        float V[9];
        for (int r = 0; r < 3; ++r) { V[r * 3 + 0] = v1[r]; V[r * 3 + 1] = v2[r]; V[r * 3 + 2] = v3[r]; }
        float dV = det3(V);
        float sV = (dV > 0.f) ? 1.f : ((dV < 0.f) ? -1.f : 0.f);
        V[2] *= sV; V[5] *= sV; V[8] *= sV;
        float Ev1[3], Ev2[3];
        for (int r = 0; r < 3; ++r) {
            Ev1[r] = E[r * 3] * V[0] + E[r * 3 + 1] * V[3] + E[r * 3 + 2] * V[6];
            Ev2[r] = E[r * 3] * V[1] + E[r * 3 + 1] * V[4] + E[r * 3 + 2] * V[7];
        }
        float s1n = sqrtf(Ev1[0] * Ev1[0] + Ev1[1] * Ev1[1] + Ev1[2] * Ev1[2]);
        float s2n = sqrtf(Ev2[0] * Ev2[0] + Ev2[1] * Ev2[1] + Ev2[2] * Ev2[2]);
        float s_avg = (s1n + s2n) * 0.5f;
        float u1[3], u2[3];
        for (int r = 0; r < 3; ++r) { u1[r] = Ev1[r] / (s1n + EPSF); u2[r] = Ev2[r] / (s2n + EPSF); }
        for (int r = 0; r < 3; ++r)
            for (int c = 0; c < 3; ++c)
                out[r * 3 + c] = s_avg * (u1[r] * V[c * 3 + 0] + u2[r] * V[c * 3 + 1]);
    }
}

extern "C" void kernel_launch(void* const* d_in, const int* in_sizes, int n_in,
                              void* d_out, int out_size, void* d_ws, size_t ws_size,
                              hipStream_t stream)
{
    const float* P = (const float*)d_in[0];
    const float* K = (const float*)d_in[1];
    float* out = (float*)d_out;

    float* fws    = (float*)d_ws;
    float* tr     = fws;                       // N
    float* tc     = tr + NPV;                  // N
    float* cand_v = tc + NPV;                  // 4N
    float* roww   = cand_v + 4 * NPV;          // 4N
    float* w1     = roww + 4 * NPV;            // N
    int*   cand_j = (int*)(w1 + NPV);          // 4N
    int*   rowj   = cand_j + 4 * NPV;          // 4N
    int*   rowcnt = rowj + 4 * NPV;            // N
    float* part   = (float*)(rowcnt + NPV);    // nseg * N * 3

    size_t fixed_bytes = (size_t)NPV * 20 * sizeof(float);
    int nseg = 128;
    if (ws_size < fixed_bytes + (size_t)nseg * NPV * 3 * sizeof(float)) nseg = 16;
    int segrows = NPV / nseg;

    k_row_top4<<<NPV, 256, 0, stream>>>(P, tr, cand_v, cand_j);
    dim3 g2(NPV / 256, nseg);
    k_col_top3_part<<<g2, 256, 0, stream>>>(P, part, segrows);
    k_col_merge<<<NPV / 256, 256, 0, stream>>>(part, tc, nseg);
    k_filter<<<NPV / 256, 256, 0, stream>>>(tr, tc, cand_v, cand_j, rowcnt, rowj, roww, w1);
    k_final<<<1, 256, 0, stream>>>(K, rowcnt, rowj, roww, w1, out);
}

// Round 3
// 146.738 us; speedup vs baseline: 2.7270x; 2.7270x over previous
//
#include <hip/hip_runtime.h>
#include <math.h>

#define NPV 3072
#define LDP 3073
#define EPSF 1e-8f

// Branchless insert of v into sorted-descending triple (a >= b >= c).
#define INS3(v, a, b, c) do { \
    float _m1 = fminf((a), (v)); (a) = fmaxf((a), (v)); \
    float _m2 = fminf((b), _m1); (b) = fmaxf((b), _m1); \
    (c) = fmaxf((c), _m2); } while (0)

// Merge sorted triple (x,y,z) into (a,b,c).
#define MRG3(x, y, z, a, b, c) do { \
    INS3((x), a, b, c); INS3((y), a, b, c); INS3((z), a, b, c); } while (0)

// One wave per row (4 rows/block), branchless values-only top-3.
// Also zeroes rowcnt for the col pass that follows.
__global__ __launch_bounds__(256) void k_row_top3(const float* __restrict__ P,
        float* __restrict__ tr, int* __restrict__ rowcnt)
{
    int lane = threadIdx.x & 63;
    int i = blockIdx.x * 4 + (threadIdx.x >> 6);
    const float* row = P + (size_t)i * LDP;
    float a0 = -1e30f, b0 = -1e30f, c0 = -1e30f;
    float a1 = -1e30f, b1 = -1e30f, c1 = -1e30f;
    float a2 = -1e30f, b2 = -1e30f, c2 = -1e30f;
    float a3 = -1e30f, b3 = -1e30f, c3 = -1e30f;
    #pragma unroll
    for (int r = 0; r < 48; r += 4) {
        float v0 = row[(r + 0) * 64 + lane];
        float v1 = row[(r + 1) * 64 + lane];
        float v2 = row[(r + 2) * 64 + lane];
        float v3 = row[(r + 3) * 64 + lane];
        INS3(v0, a0, b0, c0);
        INS3(v1, a1, b1, c1);
        INS3(v2, a2, b2, c2);
        INS3(v3, a3, b3, c3);
    }
    MRG3(a1, b1, c1, a0, b0, c0);
    MRG3(a2, b2, c2, a0, b0, c0);
    MRG3(a3, b3, c3, a0, b0, c0);
    #pragma unroll
    for (int off = 1; off < 64; off <<= 1) {
        float xa = __shfl_xor(a0, off);
        float xb = __shfl_xor(b0, off);
        float xc = __shfl_xor(c0, off);
        MRG3(xa, xb, xc, a0, b0, c0);
    }
    if (lane == 0) { tr[i] = c0; rowcnt[i] = 0; }
}

// Rare-path candidate append (entry is in its row's top-3 and > 0.01).
#define CAND(v, i) do { \
    if ((v) >= tr[i] && (v) > 0.01f) { \
        int _s = atomicAdd(&rowcnt[i], 1); \
        if (_s < 8) { rowj[(size_t)(i) * 8 + _s] = j; roww[(size_t)(i) * 8 + _s] = (v); } \
    } } while (0)

// Column top-3 over a row segment (branchless, 8 independent triples) +
// candidate collection. grid (NPV/256, nseg).
__global__ __launch_bounds__(256) void k_col_pass(const float* __restrict__ P,
        const float* __restrict__ tr, float* __restrict__ part, int segrows,
        int* __restrict__ rowcnt, int* __restrict__ rowj, float* __restrict__ roww)
{
    int j = blockIdx.x * 256 + threadIdx.x;
    int i0 = blockIdx.y * segrows;
    float a0 = -1e30f, b0 = -1e30f, c0 = -1e30f;
    float a1 = -1e30f, b1 = -1e30f, c1 = -1e30f;
    float a2 = -1e30f, b2 = -1e30f, c2 = -1e30f;
    float a3 = -1e30f, b3 = -1e30f, c3 = -1e30f;
    float a4 = -1e30f, b4 = -1e30f, c4 = -1e30f;
    float a5 = -1e30f, b5 = -1e30f, c5 = -1e30f;
    float a6 = -1e30f, b6 = -1e30f, c6 = -1e30f;
    float a7 = -1e30f, b7 = -1e30f, c7 = -1e30f;
    for (int r = 0; r < segrows; r += 8) {
        int i = i0 + r;
        const float* col = P + (size_t)i * LDP + j;
        float v0 = col[0 * LDP];
        float v1 = col[1 * LDP];
        float v2 = col[2 * LDP];
        float v3 = col[3 * LDP];
        float v4 = col[4 * LDP];
        float v5 = col[5 * LDP];
        float v6 = col[6 * LDP];
        float v7 = col[7 * LDP];
        INS3(v0, a0, b0, c0);
        INS3(v1, a1, b1, c1);
        INS3(v2, a2, b2, c2);
        INS3(v3, a3, b3, c3);
        INS3(v4, a4, b4, c4);
        INS3(v5, a5, b5, c5);
        INS3(v6, a6, b6, c6);
        INS3(v7, a7, b7, c7);
        CAND(v0, i + 0);
        CAND(v1, i + 1);
        CAND(v2, i + 2);
        CAND(v3, i + 3);
        CAND(v4, i + 4);
        CAND(v5, i + 5);
        CAND(v6, i + 6);
        CAND(v7, i + 7);
    }
    MRG3(a1, b1, c1, a0, b0, c0);
    MRG3(a2, b2, c2, a0, b0, c0);
    MRG3(a3, b3, c3, a0, b0, c0);
    MRG3(a4, b4, c4, a0, b0, c0);
    MRG3(a5, b5, c5, a0, b0, c0);
    MRG3(a6, b6, c6, a0, b0, c0);
    MRG3(a7, b7, c7, a0, b0, c0);
    size_t o = ((size_t)blockIdx.y * NPV + j) * 3;
    part[o] = a0; part[o + 1] = b0; part[o + 2] = c0;
}

__global__ __launch_bounds__(64) void k_col_merge(const float* __restrict__ part,
        float* __restrict__ tc, int nseg)
{
    int j = blockIdx.x * 64 + threadIdx.x;
    float a = -1e30f, b = -1e30f, c = -1e30f;
    for (int s = 0; s < nseg; ++s) {
        size_t o = ((size_t)s * NPV + j) * 3;
        float x = part[o], y = part[o + 1], z = part[o + 2];
        MRG3(x, y, z, a, b, c);
    }
    tc[j] = c;
}

// One thread per row: apply tc test, sort candidates ascending-j (deterministic,
// matches jnp summation order), compact in place, compute w1.
__global__ __launch_bounds__(256) void k_filter(const float* __restrict__ tc,
        int* __restrict__ rowcnt, int* __restrict__ rowj, float* __restrict__ roww,
        float* __restrict__ w1)
{
    int i = blockIdx.x * 256 + threadIdx.x;
    if (i >= NPV) return;
    int n = rowcnt[i]; if (n > 8) n = 8;
    int js[8]; float vs[8]; int m = 0;
    for (int x = 0; x < n; ++x) {
        int j = rowj[(size_t)i * 8 + x];
        float v = roww[(size_t)i * 8 + x];
        if (v >= tc[j]) { js[m] = j; vs[m] = v; ++m; }
    }
    for (int x = 1; x < m; ++x) {
        int jx = js[x]; float vx = vs[x]; int y = x - 1;
        while (y >= 0 && js[y] > jx) { js[y + 1] = js[y]; vs[y + 1] = vs[y]; --y; }
        js[y + 1] = jx; vs[y + 1] = vx;
    }
    float s = 0.f;
    for (int x = 0; x < m; ++x) {
        rowj[(size_t)i * 8 + x] = js[x];
        roww[(size_t)i * 8 + x] = vs[x];
        s += vs[x];
    }
    rowcnt[i] = m;
    w1[i] = s;
}

__device__ float block_reduce(float v, float* red) {
    int t = threadIdx.x;
    red[t] = v;
    __syncthreads();
    for (int s = 128; s > 0; s >>= 1) {
        if (t < s) red[t] += red[t + s];
        __syncthreads();
    }
    float r = red[0];
    __syncthreads();
    return r;
}

__device__ void mat3mul(const float* A, const float* B, float* C) {
    for (int r = 0; r < 3; ++r)
        for (int c = 0; c < 3; ++c)
            C[r * 3 + c] = A[r * 3] * B[c] + A[r * 3 + 1] * B[3 + c] + A[r * 3 + 2] * B[6 + c];
}

__device__ float det3(const float* M) {
    return M[0] * (M[4] * M[8] - M[5] * M[7])
         - M[1] * (M[3] * M[8] - M[5] * M[6])
         + M[2] * (M[3] * M[7] - M[4] * M[6]);
}

__device__ void powiter3(const float* M, float* v) {
    v[0] = v[1] = v[2] = 0.57735026918962584f;
    for (int it = 0; it < 50; ++it) {
        float y0 = M[0] * v[0] + M[1] * v[1] + M[2] * v[2];
        float y1 = M[3] * v[0] + M[4] * v[1] + M[5] * v[2];
        float y2 = M[6] * v[0] + M[7] * v[1] + M[8] * v[2];
        float n = sqrtf(y0 * y0 + y1 * y1 + y2 * y2) + EPSF;
        v[0] = y0 / n; v[1] = y1 / n; v[2] = y2 / n;
    }
}

__global__ __launch_bounds__(256) void k_final(const float* __restrict__ Kmat,
        const int* __restrict__ rowcnt, const int* __restrict__ rowj,
        const float* __restrict__ roww, const float* __restrict__ w1g,
        float* __restrict__ out)
{
    __shared__ float sW2[NPV];
    __shared__ float red[256];
    __shared__ float sKi[9];
    __shared__ float sPar[6];
    __shared__ float sMs[81];
    __shared__ float sV9[9];
    __shared__ float sMred[4 * 45];
    int t = threadIdx.x;

    if (t == 0) {
        float k00 = Kmat[0], k01 = Kmat[1], k02 = Kmat[2];
        float k10 = Kmat[3], k11 = Kmat[4], k12 = Kmat[5];
        float k20 = Kmat[6], k21 = Kmat[7], k22 = Kmat[8];
        float det = k00 * (k11 * k22 - k12 * k21) - k01 * (k10 * k22 - k12 * k20) + k02 * (k10 * k21 - k11 * k20);
        float id = 1.0f / det;
        sKi[0] = (k11 * k22 - k12 * k21) * id; sKi[1] = (k02 * k21 - k01 * k22) * id; sKi[2] = (k01 * k12 - k02 * k11) * id;
        sKi[3] = (k12 * k20 - k10 * k22) * id; sKi[4] = (k00 * k22 - k02 * k20) * id; sKi[5] = (k02 * k10 - k00 * k12) * id;
        sKi[6] = (k10 * k21 - k11 * k20) * id; sKi[7] = (k01 * k20 - k00 * k21) * id; sKi[8] = (k00 * k11 - k01 * k10) * id;
    }
    for (int j = t; j < NPV; j += 256) sW2[j] = 0.f;
    __syncthreads();

    for (int i = t; i < NPV; i += 256) {
        int n = rowcnt[i];
        for (int x = 0; x < n; ++x) atomicAdd(&sW2[rowj[(size_t)i * 8 + x]], roww[(size_t)i * 8 + x]);
    }
    __syncthreads();

    auto PX = [&](int i) -> float {
        float x = (float)(i & 63), y = (float)(i >> 6);
        return sKi[0] * x + sKi[1] * y + sKi[2];
    };
    auto PY = [&](int i) -> float {
        float x = (float)(i & 63), y = (float)(i >> 6);
        return sKi[3] * x + sKi[4] * y + sKi[5];
    };

    for (int set = 0; set < 2; ++set) {
        float sw = 0.f, sx = 0.f, sy = 0.f;
        for (int i = t; i < NPV; i += 256) {
            float w = set ? sW2[i] : w1g[i];
            sw += w; sx += w * PX(i); sy += w * PY(i);
        }
        sw = block_reduce(sw, red);
        sx = block_reduce(sx, red);
        sy = block_reduce(sy, red);
        float ws = sw + EPSF;
        float cx = sx / ws, cy = sy / ws;
        float smd = 0.f;
        for (int i = t; i < NPV; i += 256) {
            float w = set ? sW2[i] : w1g[i];
            float dx = PX(i) - cx, dy = PY(i) - cy;
            smd += w * (dx * dx + dy * dy);
        }
        smd = block_reduce(smd, red);
        float md = sqrtf(smd / ws + EPSF);
        float sH = 1.4142135623730951f / (md + EPSF);
        if (t == 0) { sPar[set * 3 + 0] = cx; sPar[set * 3 + 1] = cy; sPar[set * 3 + 2] = sH; }
        __syncthreads();
    }

    float c1x = sPar[0], c1y = sPar[1], s1 = sPar[2];
    float c2x = sPar[3], c2y = sPar[4], s2 = sPar[5];

    float acc[45];
    #pragma unroll
    for (int k = 0; k < 45; ++k) acc[k] = 0.f;
    for (int i = t; i < NPV; i += 256) {
        int n = rowcnt[i];
        if (n == 0) continue;
        float f1[3];
        f1[0] = (PX(i) - c1x) * s1;
        f1[1] = (PY(i) - c1y) * s1;
        f1[2] = 1.f;
        for (int e = 0; e < n; ++e) {
            int j = rowj[(size_t)i * 8 + e];
            float w = roww[(size_t)i * 8 + e];
            float f2[3];
            f2[0] = (PX(j) - c2x) * s2;
            f2[1] = (PY(j) - c2y) * s2;
            f2[2] = 1.f;
            float a[9];
            #pragma unroll
            for (int u = 0; u < 3; ++u)
                #pragma unroll
                for (int v = 0; v < 3; ++v) a[u * 3 + v] = f1[u] * f2[v];
            int idx = 0;
            #pragma unroll
            for (int u = 0; u < 9; ++u) {
                float wa = w * a[u];
                #pragma unroll
                for (int v = u; v < 9; ++v) { acc[idx] = fmaf(wa, a[v], acc[idx]); ++idx; }
            }
        }
    }
    int lane = t & 63, wid = t >> 6;
    #pragma unroll
    for (int k = 0; k < 45; ++k) {
        float v = acc[k];
        v += __shfl_down(v, 32);
        v += __shfl_down(v, 16);
        v += __shfl_down(v, 8);
        v += __shfl_down(v, 4);
        v += __shfl_down(v, 2);
        v += __shfl_down(v, 1);
        if (lane == 0) sMred[wid * 45 + k] = v;
    }
    __syncthreads();
    if (t == 0) {
        float M[81];
        int idx = 0;
        for (int u = 0; u < 9; ++u)
            for (int v = u; v < 9; ++v) {
                float s = sMred[idx] + sMred[45 + idx] + sMred[90 + idx] + sMred[135 + idx];
                M[u * 9 + v] = s; M[v * 9 + u] = s;
                ++idx;
            }
        float lam = 0.f;
        for (int d = 0; d < 9; ++d) lam += M[d * 9 + d];
        for (int r = 0; r < 9; ++r)
            for (int c = 0; c < 9; ++c)
                sMs[r * 9 + c] = (r == c ? lam : 0.f) - M[r * 9 + c];
    }
    __syncthreads();

    if (t < 64) {
        float mrow[9];
        #pragma unroll
        for (int c = 0; c < 9; ++c) mrow[c] = (t < 9) ? sMs[t * 9 + c] : 0.f;
        float v = (t < 9) ? (1.f / 3.f) : 0.f;
        for (int it = 0; it < 50; ++it) {
            float y = 0.f;
            #pragma unroll
            for (int c = 0; c < 9; ++c) y = fmaf(mrow[c], __shfl(v, c, 64), y);
            float q = (t < 9) ? y * y : 0.f;
            q += __shfl_xor(q, 1);
            q += __shfl_xor(q, 2);
            q += __shfl_xor(q, 4);
            q += __shfl_xor(q, 8);
            float n = sqrtf(q) + EPSF;
            v = y / n;
        }
        if (t < 9) sV9[t] = v;
    }
    __syncthreads();

    if (t == 0) {
        float Er[9];
        for (int k = 0; k < 9; ++k) Er[k] = sV9[k];
        float T1[9]  = { s1, 0.f, -s1 * c1x,   0.f, s1, -s1 * c1y,   0.f, 0.f, 1.f };
        float T2t[9] = { s2, 0.f, 0.f,   0.f, s2, 0.f,   -s2 * c2x, -s2 * c2y, 1.f };
        float M1[9], E[9];
        mat3mul(Er, T1, M1);
        mat3mul(T2t, M1, E);

        float B[9];
        for (int r = 0; r < 3; ++r)
            for (int c = 0; c < 3; ++c)
                B[r * 3 + c] = E[r] * E[c] + E[3 + r] * E[3 + c] + E[6 + r] * E[6 + c];
        float lam3 = B[0] + B[4] + B[8];
        float v1[3], v3[3], v2[3];
        powiter3(B, v1);
        float Bs[9];
        for (int k = 0; k < 9; ++k) Bs[k] = -B[k];
        Bs[0] += lam3; Bs[4] += lam3; Bs[8] += lam3;
        powiter3(Bs, v3);
        v2[0] = v3[1] * v1[2] - v3[2] * v1[1];
        v2[1] = v3[2] * v1[0] - v3[0] * v1[2];
        v2[2] = v3[0] * v1[1] - v3[1] * v1[0];
        float n2 = sqrtf(v2[0] * v2[0] + v2[1] * v2[1] + v2[2] * v2[2]) + EPSF;
        v2[0] /= n2; v2[1] /= n2; v2[2] /= n2;
        float V[9];
        for (int r = 0; r < 3; ++r) { V[r * 3 + 0] = v1[r]; V[r * 3 + 1] = v2[r]; V[r * 3 + 2] = v3[r]; }
        float dV = det3(V);
        float sV = (dV > 0.f) ? 1.f : ((dV < 0.f) ? -1.f : 0.f);
        V[2] *= sV; V[5] *= sV; V[8] *= sV;
        float Ev1[3], Ev2[3];
        for (int r = 0; r < 3; ++r) {
            Ev1[r] = E[r * 3] * V[0] + E[r * 3 + 1] * V[3] + E[r * 3 + 2] * V[6];
            Ev2[r] = E[r * 3] * V[1] + E[r * 3 + 1] * V[4] + E[r * 3 + 2] * V[7];
        }
        float s1n = sqrtf(Ev1[0] * Ev1[0] + Ev1[1] * Ev1[1] + Ev1[2] * Ev1[2]);
        float s2n = sqrtf(Ev2[0] * Ev2[0] + Ev2[1] * Ev2[1] + Ev2[2] * Ev2[2]);
        float s_avg = (s1n + s2n) * 0.5f;
        float u1[3], u2[3];
        for (int r = 0; r < 3; ++r) { u1[r] = Ev1[r] / (s1n + EPSF); u2[r] = Ev2[r] / (s2n + EPSF); }
        for (int r = 0; r < 3; ++r)
            for (int c = 0; c < 3; ++c)
                out[r * 3 + c] = s_avg * (u1[r] * V[c * 3 + 0] + u2[r] * V[c * 3 + 1]);
    }
}

extern "C" void kernel_launch(void* const* d_in, const int* in_sizes, int n_in,
                              void* d_out, int out_size, void* d_ws, size_t ws_size,
                              hipStream_t stream)
{
    const float* P = (const float*)d_in[0];
    const float* K = (const float*)d_in[1];
    float* out = (float*)d_out;

    float* fws    = (float*)d_ws;
    float* tr     = fws;                      // N
    float* tc     = tr + NPV;                 // N
    float* w1     = tc + NPV;                 // N
    float* roww   = w1 + NPV;                 // 8N
    int*   rowj   = (int*)(roww + 8 * NPV);   // 8N
    int*   rowcnt = rowj + 8 * NPV;           // N
    float* part   = (float*)(rowcnt + NPV);   // 3N * nseg

    size_t fixed_bytes = (size_t)NPV * 19 * sizeof(float);   // ~228 KB
    int nseg = 16;
    for (int cand = 128; cand >= 16; cand >>= 1) {
        if (ws_size >= fixed_bytes + (size_t)cand * NPV * 3 * sizeof(float)) { nseg = cand; break; }
    }
    int segrows = NPV / nseg;   // 24 / 48 / 96 / 192, all divisible by 8

    k_row_top3<<<NPV / 4, 256, 0, stream>>>(P, tr, rowcnt);
    dim3 g2(NPV / 256, nseg);
    k_col_pass<<<g2, 256, 0, stream>>>(P, tr, part, segrows, rowcnt, rowj, roww);
    k_col_merge<<<NPV / 64, 64, 0, stream>>>(part, tc, nseg);
    k_filter<<<NPV / 256, 256, 0, stream>>>(tc, rowcnt, rowj, roww, w1);
    k_final<<<1, 256, 0, stream>>>(K, rowcnt, rowj, roww, w1, out);
}